// Round 12
// baseline (1921.269 us; speedup 1.0000x reference)
//
#include <hip/hip_runtime.h>
#include <hip/hip_bf16.h>
#include <math.h>

// RWKV-7 TimeMix. R15: CHUNKED wkv7 — phase A (parallel per-chunk summaries:
// m, C, P, Bc, Zc, D via vector chains at full occupancy) + phase B (48
// serial chains of pure MFMA over 128 chunks: y^T = Mm^T St0 + C^T V^T;
// St' = diag(D)St0 + Bc(Zc^T St0) + P V^T). Replaces the 2048-step serial
// scan (~350us floor) with ~52 MFMA per chunk. gn's rk-scalar moved into
// kkprep to free r_/kbuf slots for chunk summaries.
// B=4 T=2048 C=768 H=12 N=64, LAYER_ID=1.

#define B_  4
#define T_  2048
#define C_  768
#define H_  12
#define L_  16
#define NCH 128            // chunks per (b,h)
#define NCID (48 * NCH)    // 6144 total chunks

typedef __attribute__((ext_vector_type(8))) short bf16x8;
typedef __attribute__((ext_vector_type(4))) float f32x4;

#define GLD16(gsrc, ldst)                                                     \
  __builtin_amdgcn_global_load_lds(                                           \
      (const __attribute__((address_space(1))) void*)(gsrc),                  \
      (__attribute__((address_space(3))) void*)(ldst), 16, 0, 0)

// ---- DPP helpers ----
template <int CTRL>
static __device__ __forceinline__ float row_ror_add(float v) {
  int t = __builtin_amdgcn_update_dpp(0, __float_as_int(v), CTRL, 0xF, 0xF, true);
  return v + __int_as_float(t);
}
static __device__ __forceinline__ float row_sum16(float v) {
  v = row_ror_add<0x128>(v);
  v = row_ror_add<0x124>(v);
  v = row_ror_add<0x122>(v);
  v = row_ror_add<0x121>(v);
  return v;
}

static __device__ __forceinline__ short bf16b(float f) {
  __hip_bfloat16 h = __float2bfloat16(f);
  return *reinterpret_cast<short*>(&h);
}
static __device__ __forceinline__ float bf2f(short s) {
  const unsigned u = ((unsigned)(unsigned short)s) << 16;
  return __int_as_float((int)u);
}

enum { EPI_NONE = 0, EPI_TANH, EPI_WDECAY, EPI_SIGBIAS, EPI_SIGMOID, EPI_VMIX };

static __device__ __forceinline__ float apply_epi_f(int epi, float val, int n,
                                                    int gmrow, int N,
                                                    const float* bias,
                                                    const float* ex1,
                                                    const float* ex2) {
  if (epi == EPI_TANH) {
    val = tanhf(val);
  } else if (epi == EPI_WDECAY) {
    const float u = bias[n] + val;
    const float sig = 1.f / (1.f + expf(-u));
    val = expf(-0.60653065971263342f * sig);
  } else if (epi == EPI_SIGBIAS) {
    const float u = bias[n] + val;
    val = 1.f / (1.f + expf(-u));
  } else if (epi == EPI_SIGMOID) {
    val = 1.f / (1.f + expf(-val));
  } else if (epi == EPI_VMIX) {
    const float u = bias[n] + val;
    const float sg = 1.f / (1.f + expf(-u));
    const size_t off = (size_t)gmrow * N + n;
    const float v0v = ex1[off];
    const float vf = ex2[off];
    val = v0v + (vf - v0v) * sg;
  }
  return val;
}

// ---------------- bf16 MFMA GEMM tile bodies ----------------
static __device__ __forceinline__ void gemm128_tile(
    const short* __restrict__ A, const short* __restrict__ Bw,
    float* __restrict__ C, short* __restrict__ C16, int M, int N, int K,
    int bx, int by, int epi, const float* bias, const float* ex1,
    const float* ex2, short* As, short* Bs) {
  const int tid = threadIdx.x;
  const int wave = tid >> 6, lane = tid & 63;
  const int m0 = by * 128, n0 = bx * 128;
  const int wm = (wave >> 1) * 64, wn = (wave & 1) * 64;
  const int fr = lane & 15, fk = (lane >> 4) * 8;

  f32x4 acc[4][4];
#pragma unroll
  for (int i = 0; i < 4; i++)
#pragma unroll
    for (int j = 0; j < 4; j++) acc[i][j] = (f32x4){0.f, 0.f, 0.f, 0.f};

  const int srow = tid >> 2, scol = (tid & 3) * 8;
  const short* gA = A + (size_t)(m0 + srow) * K + scol;
  const short* gB = Bw + (size_t)(n0 + srow) * K + scol;
  short* lA0 = &As[wave * 512];
  short* lA1 = &As[2048 + wave * 512];
  short* lB0 = &Bs[wave * 512];
  short* lB1 = &Bs[2048 + wave * 512];

  for (int k0 = 0; k0 < K; k0 += 32) {
    GLD16(gA + k0, lA0);
    GLD16(gA + (size_t)64 * K + k0, lA1);
    GLD16(gB + k0, lB0);
    GLD16(gB + (size_t)64 * K + k0, lB1);
    __syncthreads();

    bf16x8 af[4], bf[4];
#pragma unroll
    for (int i = 0; i < 4; i++)
      af[i] = *(const bf16x8*)&As[(wm + i * 16 + fr) * 32 + fk];
#pragma unroll
    for (int j = 0; j < 4; j++)
      bf[j] = *(const bf16x8*)&Bs[(wn + j * 16 + fr) * 32 + fk];
#pragma unroll
    for (int i = 0; i < 4; i++)
#pragma unroll
      for (int j = 0; j < 4; j++)
        acc[i][j] =
            __builtin_amdgcn_mfma_f32_16x16x32_bf16(af[i], bf[j], acc[i][j], 0, 0, 0);
    __syncthreads();
  }

  // C/D layout: col = lane&15, row = (lane>>4)*4 + reg  [m89/m91 verified]
#pragma unroll
  for (int i = 0; i < 4; i++) {
    const int gm = m0 + wm + i * 16 + (lane >> 4) * 4;
#pragma unroll
    for (int j = 0; j < 4; j++) {
      const int gn = n0 + wn + j * 16 + fr;
#pragma unroll
      for (int rix = 0; rix < 4; rix++) {
        float val = acc[i][j][rix];
        val = apply_epi_f(epi, val, gn, gm + rix, N, bias, ex1, ex2);
        C[(size_t)(gm + rix) * N + gn] = val;
        if (C16) C16[(size_t)(gm + rix) * N + gn] = bf16b(val);
      }
    }
  }
}

static __device__ __forceinline__ void gemm64_tile(
    const short* __restrict__ A, const short* __restrict__ Bw,
    short* __restrict__ out16, int M, int N, int K, int bx, int by, int epi,
    short* As, short* Bs) {
  const int tid = threadIdx.x;
  const int wave = tid >> 6, lane = tid & 63;
  const int m0 = by * 128, n0 = bx * 64;
  const int wm = (wave >> 1) * 64, wn = (wave & 1) * 32;
  const int fr = lane & 15, fk = (lane >> 4) * 8;

  f32x4 acc[4][2];
#pragma unroll
  for (int i = 0; i < 4; i++)
#pragma unroll
    for (int j = 0; j < 2; j++) acc[i][j] = (f32x4){0.f, 0.f, 0.f, 0.f};

  const int srow = tid >> 2, scol = (tid & 3) * 8;
  const short* gA = A + (size_t)(m0 + srow) * K + scol;
  const short* gB = Bw + (size_t)(n0 + srow) * K + scol;
  short* lA0 = &As[wave * 512];
  short* lA1 = &As[2048 + wave * 512];
  short* lB0 = &Bs[wave * 512];

  for (int k0 = 0; k0 < K; k0 += 32) {
    GLD16(gA + k0, lA0);
    GLD16(gA + (size_t)64 * K + k0, lA1);
    GLD16(gB + k0, lB0);
    __syncthreads();

    bf16x8 af[4], bf[2];
#pragma unroll
    for (int i = 0; i < 4; i++)
      af[i] = *(const bf16x8*)&As[(wm + i * 16 + fr) * 32 + fk];
#pragma unroll
    for (int j = 0; j < 2; j++)
      bf[j] = *(const bf16x8*)&Bs[(wn + j * 16 + fr) * 32 + fk];
#pragma unroll
    for (int i = 0; i < 4; i++)
#pragma unroll
      for (int j = 0; j < 2; j++)
        acc[i][j] =
            __builtin_amdgcn_mfma_f32_16x16x32_bf16(af[i], bf[j], acc[i][j], 0, 0, 0);
    __syncthreads();
  }

#pragma unroll
  for (int i = 0; i < 4; i++) {
    const int gm = m0 + wm + i * 16 + (lane >> 4) * 4;
#pragma unroll
    for (int j = 0; j < 2; j++) {
      const int gn = n0 + wn + j * 16 + fr;
#pragma unroll
      for (int rix = 0; rix < 4; rix++) {
        float val = acc[i][j][rix];
        if (epi == EPI_TANH) val = tanhf(val);
        else if (epi == EPI_SIGMOID) val = 1.f / (1.f + expf(-val));
        out16[(size_t)(gm + rix) * N + gn] = bf16b(val);
      }
    }
  }
}

// ---------------- merged GEMM kernels ----------------
__global__ __launch_bounds__(256) void big3_k(
    const short* __restrict__ xr, const short* __restrict__ xk,
    const short* __restrict__ xv, const short* __restrict__ wrb,
    const short* __restrict__ wkb, const short* __restrict__ wvb,
    float* __restrict__ r_, float* __restrict__ kbuf,
    float* __restrict__ vbuf, short* __restrict__ vbuf16) {
  __shared__ short smem[2 * 128 * 32];
  const int role = blockIdx.x / 6, bx = blockIdx.x % 6;
  const short* A;
  const short* Bw;
  float* C;
  short* C16 = nullptr;
  if (role == 0) { A = xr; Bw = wrb; C = r_; }
  else if (role == 1) { A = xk; Bw = wkb; C = kbuf; }
  else { A = xv; Bw = wvb; C = vbuf; C16 = vbuf16; }
  gemm128_tile(A, Bw, C, C16, B_ * T_, C_, C_, bx, blockIdx.y, EPI_NONE,
               nullptr, nullptr, nullptr, smem, smem + 128 * 32);
}

__global__ __launch_bounds__(256) void s1x4_k(
    const short* __restrict__ xw, const short* __restrict__ xa,
    const short* __restrict__ xg, const short* __restrict__ vbuf16,
    const short* __restrict__ wAT, const short* __restrict__ aAT,
    const short* __restrict__ gAT, const short* __restrict__ vAT,
    short* __restrict__ h_w, short* __restrict__ h_a,
    short* __restrict__ h_g, short* __restrict__ h_v) {
  __shared__ short smem[128 * 32 + 64 * 32];
  const int bx = blockIdx.x;  // 0..4
  const short* A;
  const short* Bw;
  short* O;
  int N, tb, epi;
  if (bx == 0)      { A = xw;     Bw = wAT; O = h_w; N = 64;  tb = 0; epi = EPI_TANH; }
  else if (bx == 1) { A = xa;     Bw = aAT; O = h_a; N = 64;  tb = 0; epi = EPI_NONE; }
  else if (bx == 2) { A = xg;     Bw = gAT; O = h_g; N = 128; tb = 0; epi = EPI_SIGMOID; }
  else if (bx == 3) { A = xg;     Bw = gAT; O = h_g; N = 128; tb = 1; epi = EPI_SIGMOID; }
  else              { A = vbuf16; Bw = vAT; O = h_v; N = 64;  tb = 0; epi = EPI_NONE; }
  gemm64_tile(A, Bw, O, B_ * T_, N, C_, tb, blockIdx.y, epi, smem,
              smem + 128 * 32);
}

__global__ __launch_bounds__(256) void s2x3_k(
    const short* __restrict__ h_v, const short* __restrict__ h_w,
    const short* __restrict__ h_a, const short* __restrict__ vBT,
    const short* __restrict__ wBT, const short* __restrict__ aBT,
    float* __restrict__ vbuf, float* __restrict__ dec_, float* __restrict__ a_,
    const float* __restrict__ v_miu, const float* __restrict__ w_miu,
    const float* __restrict__ a_miu, const float* __restrict__ v_first) {
  __shared__ short smem[2 * 128 * 32];
  const int role = blockIdx.x / 6, bx = blockIdx.x % 6;
  const short* A;
  const short* Bw;
  float* C;
  const float* bias;
  const float* ex1 = nullptr;
  const float* ex2 = nullptr;
  int epi;
  if (role == 0) { A = h_v; Bw = vBT; C = vbuf; bias = v_miu; ex1 = vbuf; ex2 = v_first; epi = EPI_VMIX; }
  else if (role == 1) { A = h_w; Bw = wBT; C = dec_; bias = w_miu; epi = EPI_WDECAY; }
  else { A = h_a; Bw = aBT; C = a_; bias = a_miu; epi = EPI_SIGBIAS; }
  gemm128_tile(A, Bw, C, nullptr, B_ * T_, C_, 64, bx, blockIdx.y, epi, bias,
               ex1, ex2, smem, smem + 128 * 32);
}

__global__ __launch_bounds__(256) void outp_k(
    const short* __restrict__ ymb, const short* __restrict__ wob,
    float* __restrict__ out) {
  __shared__ short smem[2 * 128 * 32];
  gemm128_tile(ymb, wob, out, nullptr, B_ * T_, C_, C_, blockIdx.x,
               blockIdx.y, EPI_NONE, nullptr, nullptr, nullptr, smem,
               smem + 128 * 32);
}

// ---------------- mix -> bf16 (6 lambdas, one pass) ----------------
__global__ __launch_bounds__(256) void mix6_k(
    const float* __restrict__ x, const float* __restrict__ lr,
    const float* __restrict__ lk, const float* __restrict__ lv,
    const float* __restrict__ lw, const float* __restrict__ la,
    const float* __restrict__ lg, short* __restrict__ xr,
    short* __restrict__ xk, short* __restrict__ xv, short* __restrict__ xw,
    short* __restrict__ xa, short* __restrict__ xg) {
  const int i = blockIdx.x * 256 + threadIdx.x;  // float4 index
  const int c4 = i % (C_ / 4);
  const int gm = i / (C_ / 4);
  const float4 xa4 = ((const float4*)x)[i];
  float4 xp = make_float4(0.f, 0.f, 0.f, 0.f);
  if ((gm % T_) != 0) xp = ((const float4*)x)[i - C_ / 4];
  const float4 dx =
      make_float4(xp.x - xa4.x, xp.y - xa4.y, xp.z - xa4.z, xp.w - xa4.w);

#define MIXOUT(dst, lam)                                                      \
  {                                                                           \
    const float4 l4 = ((const float4*)lam)[c4];                               \
    short4 o = {bf16b(fmaf(dx.x, l4.x, xa4.x)),                               \
                bf16b(fmaf(dx.y, l4.y, xa4.y)),                               \
                bf16b(fmaf(dx.z, l4.z, xa4.z)),                               \
                bf16b(fmaf(dx.w, l4.w, xa4.w))};                              \
    ((short4*)dst)[i] = o;                                                    \
  }
  MIXOUT(xr, lr);
  MIXOUT(xk, lk);
  MIXOUT(xv, lv);
  MIXOUT(xw, lw);
  MIXOUT(xa, la);
  MIXOUT(xg, lg);
#undef MIXOUT
}

// ------------- weights prep: 4 straight converts + 8 transposes ----------
__global__ __launch_bounds__(256) void wprep_k(
    const float* __restrict__ W_r, const float* __restrict__ W_k,
    const float* __restrict__ W_v, const float* __restrict__ W_o,
    const float* __restrict__ w_A, const float* __restrict__ a_A,
    const float* __restrict__ v_A, const float* __restrict__ g_A,
    const float* __restrict__ w_B, const float* __restrict__ a_B,
    const float* __restrict__ v_B, const float* __restrict__ g_B,
    short* __restrict__ wrb, short* __restrict__ wkb,
    short* __restrict__ wvb, short* __restrict__ wob,
    short* __restrict__ wAT, short* __restrict__ aAT,
    short* __restrict__ vAT, short* __restrict__ gAT,
    short* __restrict__ wBT, short* __restrict__ aBT,
    short* __restrict__ vBT, short* __restrict__ gBT) {
  const int job = blockIdx.y;
  const int WN = C_ * C_;
  if (job < 4) {
    const float* src = (job == 0) ? W_r : (job == 1) ? W_k : (job == 2) ? W_v : W_o;
    short* dst = (job == 0) ? wrb : (job == 1) ? wkb : (job == 2) ? wvb : wob;
    const int n4 = WN / 4;
    for (int i = blockIdx.x * 256 + threadIdx.x; i < n4; i += gridDim.x * 256) {
      const float4 v = ((const float4*)src)[i];
      short4 o = {bf16b(v.x), bf16b(v.y), bf16b(v.z), bf16b(v.w)};
      ((short4*)dst)[i] = o;
    }
  } else {
    const float* in;
    short* out;
    int R, Cc;
    switch (job) {
      case 4: in = w_A; out = wAT; R = C_; Cc = 64; break;
      case 5: in = a_A; out = aAT; R = C_; Cc = 64; break;
      case 6: in = v_A; out = vAT; R = C_; Cc = 64; break;
      case 7: in = g_A; out = gAT; R = C_; Cc = 128; break;
      case 8: in = w_B; out = wBT; R = 64; Cc = C_; break;
      case 9: in = a_B; out = aBT; R = 64; Cc = C_; break;
      case 10: in = v_B; out = vBT; R = 64; Cc = C_; break;
      default: in = g_B; out = gBT; R = 128; Cc = C_; break;
    }
    const int n = R * Cc;
    for (int i = blockIdx.x * 256 + threadIdx.x; i < n; i += gridDim.x * 256) {
      const int r = i / Cc, c = i % Cc;
      out[(size_t)c * R + r] = bf16b(in[i]);
    }
  }
}

// ---------------- kk prep: packed bf16 + rk-scalar ----------------
__global__ __launch_bounds__(256) void kkprep_k(
    const float* __restrict__ k0, const float* __restrict__ av_,
    const float* __restrict__ rr, const float* __restrict__ k_k,
    const float* __restrict__ k_a, const float* __restrict__ r_k,
    short* __restrict__ zb16, short* __restrict__ kr16,
    float* __restrict__ s_rk) {
  const int tid = threadIdx.x;
  const int wv = tid >> 6, l = tid & 63;
  const int grp = l >> 4, g16 = l & 15;
  const size_t hid = (size_t)blockIdx.x * 16 + wv * 4 + grp;
  const int h = (int)(hid % H_);
  const size_t base = hid * 64 + g16 * 4;
  const int cc = h * 64 + g16 * 4;

  const float4 kv = *(const float4*)(k0 + base);
  const float4 aa = *(const float4*)(av_ + base);
  const float4 rv = *(const float4*)(rr + base);
  const float4 kkc = *(const float4*)(k_k + cc);
  const float4 kac = *(const float4*)(k_a + cc);
  const float4 rk4 = *(const float4*)(r_k + cc);

  const float kkx = kv.x * kkc.x, kky = kv.y * kkc.y, kkz = kv.z * kkc.z,
              kkw = kv.w * kkc.w;
  const float ssp = kkx * kkx + kky * kky + kkz * kkz + kkw * kkw;
  const float ss = row_sum16(ssp);
  const float denom = fmaxf(sqrtf(ss), 1e-12f);
  const float nx = kkx / denom, ny = kky / denom, nz = kkz / denom,
              nw = kkw / denom;

  bf16x8 zb = {bf16b(-nx), bf16b(-ny), bf16b(-nz), bf16b(-nw),
               bf16b(nx * aa.x), bf16b(ny * aa.y), bf16b(nz * aa.z),
               bf16b(nw * aa.w)};
  *(bf16x8*)(zb16 + hid * 128 + g16 * 8) = zb;

  const float knx = kv.x * (1.f + (aa.x - 1.f) * kac.x);
  const float kny = kv.y * (1.f + (aa.y - 1.f) * kac.y);
  const float knz = kv.z * (1.f + (aa.z - 1.f) * kac.z);
  const float knw = kv.w * (1.f + (aa.w - 1.f) * kac.w);
  bf16x8 kr = {bf16b(knx), bf16b(kny), bf16b(knz), bf16b(knw),
               bf16b(rv.x), bf16b(rv.y), bf16b(rv.z), bf16b(rv.w)};
  *(bf16x8*)(kr16 + hid * 128 + g16 * 8) = kr;

  // rk-scalar for gn: s = sum(r * k_mod * r_k) over the 64 cols
  const float sp = rv.x * knx * rk4.x + rv.y * kny * rk4.y +
                   rv.z * knz * rk4.z + rv.w * knw * rk4.w;
  const float sv = row_sum16(sp);
  if (g16 == 0) s_rk[hid] = sv;
}

// ---------------- phase A: per-chunk summaries (parallel) ----------------
// One wave per chunk; 4 groups of 16 lanes split the chains (4 cols/lane).
// Outputs (per cid): m (bf16 [t][64] col-major-by-t), Zc/Bc/P (bf16 [i][64]),
// C (f32 [t*16+i], i<=t only), D (f32 [64]).
__global__ __launch_bounds__(256) void phaseA_k(
    const float* __restrict__ dd, const short* __restrict__ zb16,
    const short* __restrict__ kr16, short* __restrict__ m16,
    short* __restrict__ Zc16, short* __restrict__ Bc16,
    short* __restrict__ P16, float* __restrict__ Cbuf,
    float* __restrict__ Dbuf) {
  const int tid = threadIdx.x;
  const int wave = tid >> 6, l = tid & 63;
  const int grp = l >> 4, l16 = l & 15;
  const int cid = blockIdx.x * 4 + wave;  // 0..6143
  const int bh = cid >> 7, c = cid & (NCH - 1);
  const int b = bh / H_, h = bh % H_;
  const size_t tok0 = (size_t)b * T_ + (size_t)c * L_;
  const size_t cbase = (size_t)cid * 256;
  const size_t vbase = (size_t)cid * 1024;

#define LD_ZB(s, z4, b4)                                                      \
  {                                                                           \
    const bf16x8 t8 =                                                         \
        *(const bf16x8*)(zb16 + ((tok0 + (s)) * H_ + h) * 128 + l16 * 8);     \
    z4 = make_float4(bf2f(t8[0]), bf2f(t8[1]), bf2f(t8[2]), bf2f(t8[3]));     \
    b4 = make_float4(bf2f(t8[4]), bf2f(t8[5]), bf2f(t8[6]), bf2f(t8[7]));     \
  }
#define LD_KR(s, k4, r4)                                                      \
  {                                                                           \
    const bf16x8 t8 =                                                         \
        *(const bf16x8*)(kr16 + ((tok0 + (s)) * H_ + h) * 128 + l16 * 8);     \
    k4 = make_float4(bf2f(t8[0]), bf2f(t8[1]), bf2f(t8[2]), bf2f(t8[3]));     \
    r4 = make_float4(bf2f(t8[4]), bf2f(t8[5]), bf2f(t8[6]), bf2f(t8[7]));     \
  }
#define LD_D(s, d4)                                                           \
  { d4 = *(const float4*)(dd + (tok0 + (s)) * C_ + h * 64 + l16 * 4); }
#define DOT4(a, b) ((a).x * (b).x + (a).y * (b).y + (a).z * (b).z + (a).w * (b).w)

  // q-chains: this group's t in {grp, grp+4, grp+8, grp+12}
  for (int tsel = 0; tsel < 4; ++tsel) {
    const int t = tsel * 4 + grp;
    float4 k4, x;
    LD_KR(t, k4, x);  // x = r_t
    {
      const float cs = row_sum16(DOT4(k4, x));
      if (l16 == 0) Cbuf[cbase + t * 16 + t] = cs;
    }
    for (int s = t; s >= 1; --s) {
      float4 z4, b4, d4, ki, ri;
      LD_ZB(s, z4, b4);
      LD_D(s, d4);
      const float bd = row_sum16(DOT4(b4, x));
      x.x = fmaf(d4.x, x.x, z4.x * bd);
      x.y = fmaf(d4.y, x.y, z4.y * bd);
      x.z = fmaf(d4.z, x.z, z4.z * bd);
      x.w = fmaf(d4.w, x.w, z4.w * bd);
      LD_KR(s - 1, ki, ri);
      const float cv = row_sum16(DOT4(ki, x));
      if (l16 == 0) Cbuf[cbase + t * 16 + (s - 1)] = cv;
    }
    {  // m_t = A_0 x
      float4 z4, b4, d4;
      LD_ZB(0, z4, b4);
      LD_D(0, d4);
      const float bd = row_sum16(DOT4(b4, x));
      x.x = fmaf(d4.x, x.x, z4.x * bd);
      x.y = fmaf(d4.y, x.y, z4.y * bd);
      x.z = fmaf(d4.z, x.z, z4.z * bd);
      x.w = fmaf(d4.w, x.w, z4.w * bd);
      short4 o = {bf16b(x.x), bf16b(x.y), bf16b(x.z), bf16b(x.w)};
      *(short4*)(m16 + vbase + t * 64 + l16 * 4) = o;
    }
  }

  // p/beta chains: this group's i in {grp, grp+4, grp+8, grp+12}
  for (int isel = 0; isel < 4; ++isel) {
    const int i = isel * 4 + grp;
    float4 xp, xb;
    {
      float4 k4, r4;
      LD_KR(i, k4, r4);
      xp = k4;
    }
    {
      float4 z4, b4;
      LD_ZB(i, z4, b4);
      xb = b4;
    }
    for (int s = i + 1; s < L_; ++s) {
      float4 z4, b4, d4;
      LD_ZB(s, z4, b4);
      LD_D(s, d4);
      const float sp = row_sum16(DOT4(z4, xp));
      const float sb = row_sum16(DOT4(z4, xb));
      xp.x = fmaf(d4.x, xp.x, b4.x * sp);
      xp.y = fmaf(d4.y, xp.y, b4.y * sp);
      xp.z = fmaf(d4.z, xp.z, b4.z * sp);
      xp.w = fmaf(d4.w, xp.w, b4.w * sp);
      xb.x = fmaf(d4.x, xb.x, b4.x * sb);
      xb.y = fmaf(d4.y, xb.y, b4.y * sb);
      xb.z = fmaf(d4.z, xb.z, b4.z * sb);
      xb.w = fmaf(d4.w, xb.w, b4.w * sb);
    }
    {
      short4 op = {bf16b(xp.x), bf16b(xp.y), bf16b(xp.z), bf16b(xp.w)};
      short4 ob = {bf16b(xb.x), bf16b(xb.y), bf16b(xb.z), bf16b(xb.w)};
      *(short4*)(P16 + vbase + i * 64 + l16 * 4) = op;
      *(short4*)(Bc16 + vbase + i * 64 + l16 * 4) = ob;
    }
  }

  // zeta (Zc) + D: cumulative decay product
  {
    float4 prod = make_float4(1.f, 1.f, 1.f, 1.f);
    for (int s = 0; s < L_; ++s) {
      if ((s & 3) == grp) {
        float4 z4, b4;
        LD_ZB(s, z4, b4);
        short4 o = {bf16b(prod.x * z4.x), bf16b(prod.y * z4.y),
                    bf16b(prod.z * z4.z), bf16b(prod.w * z4.w)};
        *(short4*)(Zc16 + vbase + s * 64 + l16 * 4) = o;
      }
      float4 d4;
      LD_D(s, d4);
      prod.x *= d4.x;
      prod.y *= d4.y;
      prod.z *= d4.z;
      prod.w *= d4.w;
    }
    if (grp == 0)
      *(float4*)(Dbuf + (size_t)cid * 64 + l16 * 4) = prod;
  }
#undef LD_ZB
#undef LD_KR
#undef LD_D
#undef DOT4
}

// ---------------- phase B: serial chains (MFMA) + s2g GEMM + copy --------
// Blocks 0..11: 48 chain waves (one per (b,h)); state St = S^T in acc
// (C-layout == B-operand layout trick). Blocks 12..59: s2-g GEMM. 60..75: copy.
#define MFMA32(a, b, c) __builtin_amdgcn_mfma_f32_16x16x32_bf16(a, b, c, 0, 0, 0)
__global__ __launch_bounds__(256, 1) void phaseB_k(
    const short* __restrict__ m16, const short* __restrict__ Zc16,
    const short* __restrict__ Bc16, const short* __restrict__ P16,
    const float* __restrict__ Cbuf, const float* __restrict__ Dbuf,
    const float* __restrict__ vbuf, float* __restrict__ yy,
    const short* __restrict__ h_g, const short* __restrict__ gBT,
    float* __restrict__ g_, const float4* __restrict__ cpsrc,
    float4* __restrict__ cpdst, int n4) {
  __shared__ short smem[2 * 128 * 32];
  const int blk = blockIdx.x;

  if (blk >= 60) {  // ---- copy role ----
    const int rb = blk - 60;
    for (int i = rb * 256 + threadIdx.x; i < n4; i += 16 * 256)
      cpdst[i] = cpsrc[i];
    return;
  }
  if (blk >= 12) {  // ---- stage2-g GEMM role ----
    const int rb = blk - 12;
    for (int it = 0; it < 8; ++it) {
      const int tile = rb + it * 48;
      gemm128_tile(h_g, gBT, g_, nullptr, B_ * T_, C_, 128, tile % 6,
                   tile / 6, EPI_NONE, nullptr, nullptr, nullptr, smem,
                   smem + 128 * 32);
    }
    return;
  }

  // ---- chain role ----
  const int wave = threadIdx.x >> 6, l = threadIdx.x & 63;
  const int bh = blk * 4 + wave;  // 0..47
  const int b = bh / H_, h = bh % H_;
  const int q = l >> 4, n16 = l & 15;

  f32x4 acc[4][4];
#pragma unroll
  for (int i = 0; i < 4; i++)
#pragma unroll
    for (int j = 0; j < 4; j++) acc[i][j] = (f32x4){0.f, 0.f, 0.f, 0.f};

  for (int c = 0; c < NCH; ++c) {
    const size_t cid = (size_t)bh * NCH + c;
    const size_t t0g = (size_t)b * T_ + (size_t)c * L_;
    const size_t vbase = cid * 1024;

    // 1) St0 -> B-operand frags (K=64 as 2 steps of 32). B[k,n]: lane holds
    //    k = q*8+e (+32*kt2), n = n16. Source acc value: tile (2kt2 + (q>>1),
    //    nt), holder lane n16 + 16*((e>>2) + 2*(q&1)), reg e&3.
    bf16x8 sf[2][4];
#pragma unroll
    for (int kt2 = 0; kt2 < 2; ++kt2) {
#pragma unroll
      for (int nt = 0; nt < 4; ++nt) {
        bf16x8 f;
#pragma unroll
        for (int e = 0; e < 8; ++e) {
          const int src = n16 + ((e >> 2) + ((q & 1) << 1)) * 16;
          const float v0 = __shfl(acc[2 * kt2 + 0][nt][e & 3], src);
          const float v1 = __shfl(acc[2 * kt2 + 1][nt][e & 3], src);
          f[e] = bf16b((q < 2) ? v0 : v1);
        }
        sf[kt2][nt] = f;
      }
    }

    // 2) V^T B-frags (K=16 padded to 32): B[k=i, n] = v_i[n]
    bf16x8 bv[4];
#pragma unroll
    for (int nt = 0; nt < 4; ++nt) {
      bf16x8 f;
#pragma unroll
      for (int e = 0; e < 8; ++e) {
        const int k = q * 8 + e;
        float v = 0.f;
        if (k < L_) v = vbuf[(t0g + k) * C_ + h * 64 + nt * 16 + n16];
        f[e] = bf16b(v);
      }
      bv[nt] = f;
    }

    // 3) Y^T = Mm^T St0 + C^T V^T   (16 x 64)
    {
      f32x4 yac[4];
#pragma unroll
      for (int nt = 0; nt < 4; ++nt) yac[nt] = (f32x4){0.f, 0.f, 0.f, 0.f};
      bf16x8 am0 = *(const bf16x8*)(m16 + vbase + n16 * 64 + 0 * 32 + q * 8);
      bf16x8 am1 = *(const bf16x8*)(m16 + vbase + n16 * 64 + 1 * 32 + q * 8);
      bf16x8 ac;
      {
        float4 c0 = make_float4(0.f, 0.f, 0.f, 0.f), c1 = c0;
        if (q < 2) {
          const float* cp = Cbuf + cid * 256 + n16 * 16 + q * 8;
          c0 = *(const float4*)cp;
          c1 = *(const float4*)(cp + 4);
        }
        const float cf[8] = {c0.x, c0.y, c0.z, c0.w, c1.x, c1.y, c1.z, c1.w};
#pragma unroll
        for (int e = 0; e < 8; ++e) {
          const int i = q * 8 + e;
          ac[e] = (q < 2 && i <= n16) ? bf16b(cf[e]) : (short)0;
        }
      }
#pragma unroll
      for (int nt = 0; nt < 4; ++nt) {
        yac[nt] = MFMA32(am0, sf[0][nt], yac[nt]);
        yac[nt] = MFMA32(am1, sf[1][nt], yac[nt]);
        yac[nt] = MFMA32(ac, bv[nt], yac[nt]);
      }
#pragma unroll
      for (int nt = 0; nt < 4; ++nt)
#pragma unroll
        for (int rix = 0; rix < 4; ++rix)
          yy[(t0g + q * 4 + rix) * C_ + h * 64 + nt * 16 + n16] =
              yac[nt][rix];
    }

    // 4) W = Zc^T St0   (16 x 64)
    f32x4 wac[4];
#pragma unroll
    for (int nt = 0; nt < 4; ++nt) wac[nt] = (f32x4){0.f, 0.f, 0.f, 0.f};
    {
      bf16x8 az0 = *(const bf16x8*)(Zc16 + vbase + n16 * 64 + 0 * 32 + q * 8);
      bf16x8 az1 = *(const bf16x8*)(Zc16 + vbase + n16 * 64 + 1 * 32 + q * 8);
#pragma unroll
      for (int nt = 0; nt < 4; ++nt) {
        wac[nt] = MFMA32(az0, sf[0][nt], wac[nt]);
        wac[nt] = MFMA32(az1, sf[1][nt], wac[nt]);
      }
    }

    // 5) St' = diag(D) St0 + Bc W + P V^T
#pragma unroll
    for (int mt = 0; mt < 4; ++mt) {
      const float4 dv = *(const float4*)(Dbuf + cid * 64 + mt * 16 + q * 4);
#pragma unroll
      for (int nt = 0; nt < 4; ++nt) {
        acc[mt][nt][0] *= dv.x;
        acc[mt][nt][1] *= dv.y;
        acc[mt][nt][2] *= dv.z;
        acc[mt][nt][3] *= dv.w;
      }
    }
    bf16x8 wf[4];
#pragma unroll
    for (int nt = 0; nt < 4; ++nt) {
      bf16x8 f;
#pragma unroll
      for (int e = 0; e < 8; ++e) {
        const int src = n16 + (((q & 1) << 1) + (e >> 2)) * 16;
        const float v = __shfl(wac[nt][e & 3], src);
        f[e] = (q < 2) ? bf16b(v) : (short)0;
      }
      wf[nt] = f;
    }
#pragma unroll
    for (int mt = 0; mt < 4; ++mt) {
      bf16x8 fb, fp;
#pragma unroll
      for (int e = 0; e < 8; ++e) {
        const int k = q * 8 + e;
        short vb = 0, vp = 0;
        if (k < L_) {
          vb = Bc16[vbase + (size_t)k * 64 + mt * 16 + n16];
          vp = P16[vbase + (size_t)k * 64 + mt * 16 + n16];
        }
        fb[e] = vb;
        fp[e] = vp;
      }
#pragma unroll
      for (int nt = 0; nt < 4; ++nt) {
        acc[mt][nt] = MFMA32(fb, wf[nt], acc[mt][nt]);
        acc[mt][nt] = MFMA32(fp, bv[nt], acc[mt][nt]);
      }
    }
  }
}

// ---------- GroupNorm + rk-scalar + gate -> bf16 ----------
__global__ __launch_bounds__(256) void gn_k(
    const float* __restrict__ y, const float* __restrict__ v,
    const float* __restrict__ g, const float* __restrict__ s_rk,
    const float* __restrict__ ln_w, const float* __restrict__ ln_b,
    short* __restrict__ ymb) {
  const int tid = threadIdx.x;
  const int wv = tid >> 6, l = tid & 63;
  const int grp = l >> 4, g16 = l & 15;
  const size_t hid = (size_t)blockIdx.x * 16 + wv * 4 + grp;
  const int h = (int)(hid % H_);
  const size_t base = hid * 64 + g16 * 4;
  const int cc = h * 64 + g16 * 4;

  const float4 y4 = *(const float4*)(y + base);
  const float4 v4 = *(const float4*)(v + base);
  const float4 g4 = *(const float4*)(g + base);
  const float4 lw4 = *(const float4*)(ln_w + cc);
  const float4 lb4 = *(const float4*)(ln_b + cc);
  const float s = s_rk[hid];

  const float mu = row_sum16(y4.x + y4.y + y4.z + y4.w) * (1.f / 64.f);
  const float sq =
      row_sum16(y4.x * y4.x + y4.y * y4.y + y4.z * y4.z + y4.w * y4.w) *
      (1.f / 64.f);
  const float inv = rsqrtf(sq - mu * mu + 0.00064f);

  short4 o;
  o.x = bf16b((fmaf((y4.x - mu) * inv, lw4.x, fmaf(s, v4.x, lb4.x))) * g4.x);
  o.y = bf16b((fmaf((y4.y - mu) * inv, lw4.y, fmaf(s, v4.y, lb4.y))) * g4.y);
  o.z = bf16b((fmaf((y4.z - mu) * inv, lw4.z, fmaf(s, v4.z, lb4.z))) * g4.z);
  o.w = bf16b((fmaf((y4.w - mu) * inv, lw4.w, fmaf(s, v4.w, lb4.w))) * g4.w);
  *(short4*)(ymb + base) = o;
}

// ---------------- host launcher ----------------
extern "C" void kernel_launch(void* const* d_in, const int* in_sizes, int n_in,
                              void* d_out, int out_size, void* d_ws,
                              size_t ws_size, hipStream_t stream) {
  const float* x       = (const float*)d_in[0];
  const float* v_first = (const float*)d_in[1];
  const float* lam_r   = (const float*)d_in[2];
  const float* lam_w   = (const float*)d_in[3];
  const float* lam_k   = (const float*)d_in[4];
  const float* lam_v   = (const float*)d_in[5];
  const float* lam_a   = (const float*)d_in[6];
  const float* lam_g   = (const float*)d_in[7];
  const float* w_miu   = (const float*)d_in[8];
  const float* w_A     = (const float*)d_in[9];
  const float* w_B     = (const float*)d_in[10];
  const float* a_miu   = (const float*)d_in[11];
  const float* a_A     = (const float*)d_in[12];
  const float* a_B     = (const float*)d_in[13];
  const float* v_miu   = (const float*)d_in[14];
  const float* v_A     = (const float*)d_in[15];
  const float* v_B     = (const float*)d_in[16];
  const float* g_A     = (const float*)d_in[17];
  const float* g_B     = (const float*)d_in[18];
  const float* k_k     = (const float*)d_in[19];
  const float* k_a     = (const float*)d_in[20];
  const float* r_k     = (const float*)d_in[21];
  const float* W_r     = (const float*)d_in[22];
  const float* W_k     = (const float*)d_in[23];
  const float* W_v     = (const float*)d_in[24];
  const float* W_o     = (const float*)d_in[25];
  const float* ln_w    = (const float*)d_in[26];
  const float* ln_b    = (const float*)d_in[27];

  const int M = B_ * T_;            // 8192
  const size_t S = (size_t)M * C_;  // 6291456

  float* ws   = (float*)d_ws;
  float* r_   = ws + 0 * S;
  float* kbuf = ws + 1 * S;
  float* vbuf = ws + 2 * S;
  float* dec_ = ws + 3 * S;
  float* a_   = ws + 4 * S;
  float* g_   = ws + 5 * S;
  float* z_   = ws + 6 * S;
  float* bb_  = ws + 7 * S;
  float* h_   = ws + 8 * S;                       // M*128 floats
  short* wb   = (short*)(h_ + (size_t)M * 128);   // bf16 weight copies
  float* out  = (float*)d_out;

  const int WN = C_ * C_;  // 589824
  short* wrb = wb + 0 * (size_t)WN;
  short* wkb = wb + 1 * (size_t)WN;
  short* wvb = wb + 2 * (size_t)WN;
  short* wob = wb + 3 * (size_t)WN;
  short* wAT = wb + 4 * (size_t)WN;
  short* aAT = wAT + (size_t)C_ * 64;
  short* vAT = aAT + (size_t)C_ * 64;
  short* gAT = vAT + (size_t)C_ * 64;
  short* wBT = gAT + (size_t)C_ * 128;
  short* aBT = wBT + (size_t)C_ * 64;
  short* vBT = aBT + (size_t)C_ * 64;
  short* gBT = vBT + (size_t)C_ * 64;

  // bf16 aliases in dead fp32 slots
  short* xr  = (short*)dec_;          // consumed (big3) before dec_ written
  short* xk  = (short*)a_;            // consumed (big3) before a_ written
  short* xv  = (short*)g_;            // consumed (big3) before h_v written
  short* xw  = (short*)z_;            // consumed (s1) before kkprep writes zb16
  short* xa  = (short*)z_ + S;
  short* xg  = (short*)bb_;
  short* vbuf16 = (short*)bb_ + S;
  short* h_w = (short*)h_;
  short* h_a = h_w + (size_t)M * 64;
  short* h_g = h_a + (size_t)M * 64;
  short* h_v = (short*)g_;            // dead before s2g writes g_
  short* zb16 = (short*)z_;           // kkprep out; phase A in
  short* kr16 = (short*)bb_;
  short* ymb = (short*)z_;            // gn out (zb16 dead after phase A)

  // chunk summaries in slots dead after kkprep (r/k raw no longer needed:
  // gn's rk-scalar is precomputed by kkprep into s_rk)
  short* m16  = (short*)kbuf;         // S shorts
  short* Zc16 = m16 + S;              // S shorts (fills kbuf slot exactly)
  short* Bc16 = (short*)r_;           // S shorts
  short* P16  = Bc16 + S;             // S shorts (fills r_ slot exactly)
  // C / D / s_rk in out[0..S) (dead until outp, which runs after gn)
  float* Cbuf = out;                              // 6144*256 floats
  float* Dbuf = Cbuf + (size_t)NCID * 256;        // 6144*64 floats
  float* s_rk = Dbuf + (size_t)NCID * 64;         // 98304 floats

  // 1) weights prep
  {
    dim3 blk(256), grid(576, 12);
    hipLaunchKernelGGL(wprep_k, grid, blk, 0, stream, W_r, W_k, W_v, W_o,
                       w_A, a_A, v_A, g_A, w_B, a_B, v_B, g_B, wrb, wkb, wvb,
                       wob, wAT, aAT, vAT, gAT, wBT, aBT, vBT, gBT);
  }
  // 2) mix
  {
    dim3 blk(256), grid((int)(S / 4 / 256));
    hipLaunchKernelGGL(mix6_k, grid, blk, 0, stream, x, lam_r, lam_k, lam_v,
                       lam_w, lam_a, lam_g, xr, xk, xv, xw, xa, xg);
  }
  // 3) big projections
  {
    dim3 blk(256), grid(18, M / 128);
    hipLaunchKernelGGL(big3_k, grid, blk, 0, stream, xr, xk, xv, wrb, wkb,
                       wvb, r_, kbuf, vbuf, vbuf16);
  }
  // 4) stage-1 low-rank
  {
    dim3 blk(256), grid(5, M / 128);
    hipLaunchKernelGGL(s1x4_k, grid, blk, 0, stream, xw, xa, xg, vbuf16, wAT,
                       aAT, gAT, vAT, h_w, h_a, h_g, h_v);
  }
  // 5) stage-2 VMIX/WDECAY/SIGBIAS
  {
    dim3 blk(256), grid(18, M / 128);
    hipLaunchKernelGGL(s2x3_k, grid, blk, 0, stream, h_v, h_w, h_a, vBT, wBT,
                       aBT, vbuf, dec_, a_, v_miu, w_miu, a_miu, v_first);
  }
  // 6) kk prep -> zb16/kr16 + s_rk
  {
    dim3 grid((B_ * T_ * H_) / 16), blk(256);
    hipLaunchKernelGGL(kkprep_k, grid, blk, 0, stream, kbuf, a_, r_, k_k,
                       k_a, r_k, zb16, kr16, s_rk);
  }
  // 7) phase A: per-chunk summaries (parallel)
  {
    dim3 grid(NCID / 4), blk(256);
    hipLaunchKernelGGL(phaseA_k, grid, blk, 0, stream, dec_, zb16, kr16,
                       m16, Zc16, Bc16, P16, Cbuf, Dbuf);
  }
  // 8) phase B: serial MFMA chains + s2g GEMM + v_first copy
  {
    dim3 grid(76), blk(256);
    hipLaunchKernelGGL(phaseB_k, grid, blk, 0, stream, m16, Zc16, Bc16, P16,
                       Cbuf, Dbuf, vbuf, a_, h_g, gBT, g_,
                       (const float4*)v_first, (float4*)(out + S),
                       (int)(S / 4));
  }
  // 9) groupnorm + rk-scalar + gate
  {
    dim3 grid((B_ * T_ * H_) / 16), blk(256);
    hipLaunchKernelGGL(gn_k, grid, blk, 0, stream, a_, vbuf, g_, s_rk,
                       ln_w, ln_b, ymb);
  }
  // 10) output projection
  {
    dim3 blk(256), grid(C_ / 128, M / 128);
    hipLaunchKernelGGL(outp_k, grid, blk, 0, stream, ymb, wob, out);
  }
}

// Round 13
// 759.246 us; speedup vs baseline: 2.5305x; 2.5305x over previous
//
#include <hip/hip_runtime.h>
#include <hip/hip_bf16.h>
#include <math.h>

// RWKV-7 TimeMix. R16: chunked wkv7 (R15 algebra, verified) with phase B
// re-executed: 48 blocks x 4 waves (column-quarter split of the state — the
// chunk recurrence is column-independent), all chunk summaries staged to LDS
// via cooperative global_load_lds (coalesced), compute verbatim from R15.
// B=4 T=2048 C=768 H=12 N=64, LAYER_ID=1.

#define B_  4
#define T_  2048
#define C_  768
#define H_  12
#define L_  16
#define NCH 128            // chunks per (b,h)
#define NCID (48 * NCH)    // 6144 total chunks

typedef __attribute__((ext_vector_type(8))) short bf16x8;
typedef __attribute__((ext_vector_type(4))) float f32x4;

#define GLD16(gsrc, ldst)                                                     \
  __builtin_amdgcn_global_load_lds(                                           \
      (const __attribute__((address_space(1))) void*)(gsrc),                  \
      (__attribute__((address_space(3))) void*)(ldst), 16, 0, 0)

// ---- DPP helpers ----
template <int CTRL>
static __device__ __forceinline__ float row_ror_add(float v) {
  int t = __builtin_amdgcn_update_dpp(0, __float_as_int(v), CTRL, 0xF, 0xF, true);
  return v + __int_as_float(t);
}
static __device__ __forceinline__ float row_sum16(float v) {
  v = row_ror_add<0x128>(v);
  v = row_ror_add<0x124>(v);
  v = row_ror_add<0x122>(v);
  v = row_ror_add<0x121>(v);
  return v;
}

static __device__ __forceinline__ short bf16b(float f) {
  __hip_bfloat16 h = __float2bfloat16(f);
  return *reinterpret_cast<short*>(&h);
}
static __device__ __forceinline__ float bf2f(short s) {
  const unsigned u = ((unsigned)(unsigned short)s) << 16;
  return __int_as_float((int)u);
}

enum { EPI_NONE = 0, EPI_TANH, EPI_WDECAY, EPI_SIGBIAS, EPI_SIGMOID, EPI_VMIX };

static __device__ __forceinline__ float apply_epi_f(int epi, float val, int n,
                                                    int gmrow, int N,
                                                    const float* bias,
                                                    const float* ex1,
                                                    const float* ex2) {
  if (epi == EPI_TANH) {
    val = tanhf(val);
  } else if (epi == EPI_WDECAY) {
    const float u = bias[n] + val;
    const float sig = 1.f / (1.f + expf(-u));
    val = expf(-0.60653065971263342f * sig);
  } else if (epi == EPI_SIGBIAS) {
    const float u = bias[n] + val;
    val = 1.f / (1.f + expf(-u));
  } else if (epi == EPI_SIGMOID) {
    val = 1.f / (1.f + expf(-val));
  } else if (epi == EPI_VMIX) {
    const float u = bias[n] + val;
    const float sg = 1.f / (1.f + expf(-u));
    const size_t off = (size_t)gmrow * N + n;
    const float v0v = ex1[off];
    const float vf = ex2[off];
    val = v0v + (vf - v0v) * sg;
  }
  return val;
}

// ---------------- bf16 MFMA GEMM tile bodies ----------------
static __device__ __forceinline__ void gemm128_tile(
    const short* __restrict__ A, const short* __restrict__ Bw,
    float* __restrict__ C, short* __restrict__ C16, int M, int N, int K,
    int bx, int by, int epi, const float* bias, const float* ex1,
    const float* ex2, short* As, short* Bs) {
  const int tid = threadIdx.x;
  const int wave = tid >> 6, lane = tid & 63;
  const int m0 = by * 128, n0 = bx * 128;
  const int wm = (wave >> 1) * 64, wn = (wave & 1) * 64;
  const int fr = lane & 15, fk = (lane >> 4) * 8;

  f32x4 acc[4][4];
#pragma unroll
  for (int i = 0; i < 4; i++)
#pragma unroll
    for (int j = 0; j < 4; j++) acc[i][j] = (f32x4){0.f, 0.f, 0.f, 0.f};

  const int srow = tid >> 2, scol = (tid & 3) * 8;
  const short* gA = A + (size_t)(m0 + srow) * K + scol;
  const short* gB = Bw + (size_t)(n0 + srow) * K + scol;
  short* lA0 = &As[wave * 512];
  short* lA1 = &As[2048 + wave * 512];
  short* lB0 = &Bs[wave * 512];
  short* lB1 = &Bs[2048 + wave * 512];

  for (int k0 = 0; k0 < K; k0 += 32) {
    GLD16(gA + k0, lA0);
    GLD16(gA + (size_t)64 * K + k0, lA1);
    GLD16(gB + k0, lB0);
    GLD16(gB + (size_t)64 * K + k0, lB1);
    __syncthreads();

    bf16x8 af[4], bf[4];
#pragma unroll
    for (int i = 0; i < 4; i++)
      af[i] = *(const bf16x8*)&As[(wm + i * 16 + fr) * 32 + fk];
#pragma unroll
    for (int j = 0; j < 4; j++)
      bf[j] = *(const bf16x8*)&Bs[(wn + j * 16 + fr) * 32 + fk];
#pragma unroll
    for (int i = 0; i < 4; i++)
#pragma unroll
      for (int j = 0; j < 4; j++)
        acc[i][j] =
            __builtin_amdgcn_mfma_f32_16x16x32_bf16(af[i], bf[j], acc[i][j], 0, 0, 0);
    __syncthreads();
  }

  // C/D layout: col = lane&15, row = (lane>>4)*4 + reg  [m89/m91 verified]
#pragma unroll
  for (int i = 0; i < 4; i++) {
    const int gm = m0 + wm + i * 16 + (lane >> 4) * 4;
#pragma unroll
    for (int j = 0; j < 4; j++) {
      const int gn = n0 + wn + j * 16 + fr;
#pragma unroll
      for (int rix = 0; rix < 4; rix++) {
        float val = acc[i][j][rix];
        val = apply_epi_f(epi, val, gn, gm + rix, N, bias, ex1, ex2);
        C[(size_t)(gm + rix) * N + gn] = val;
        if (C16) C16[(size_t)(gm + rix) * N + gn] = bf16b(val);
      }
    }
  }
}

static __device__ __forceinline__ void gemm64_tile(
    const short* __restrict__ A, const short* __restrict__ Bw,
    short* __restrict__ out16, int M, int N, int K, int bx, int by, int epi,
    short* As, short* Bs) {
  const int tid = threadIdx.x;
  const int wave = tid >> 6, lane = tid & 63;
  const int m0 = by * 128, n0 = bx * 64;
  const int wm = (wave >> 1) * 64, wn = (wave & 1) * 32;
  const int fr = lane & 15, fk = (lane >> 4) * 8;

  f32x4 acc[4][2];
#pragma unroll
  for (int i = 0; i < 4; i++)
#pragma unroll
    for (int j = 0; j < 2; j++) acc[i][j] = (f32x4){0.f, 0.f, 0.f, 0.f};

  const int srow = tid >> 2, scol = (tid & 3) * 8;
  const short* gA = A + (size_t)(m0 + srow) * K + scol;
  const short* gB = Bw + (size_t)(n0 + srow) * K + scol;
  short* lA0 = &As[wave * 512];
  short* lA1 = &As[2048 + wave * 512];
  short* lB0 = &Bs[wave * 512];

  for (int k0 = 0; k0 < K; k0 += 32) {
    GLD16(gA + k0, lA0);
    GLD16(gA + (size_t)64 * K + k0, lA1);
    GLD16(gB + k0, lB0);
    __syncthreads();

    bf16x8 af[4], bf[2];
#pragma unroll
    for (int i = 0; i < 4; i++)
      af[i] = *(const bf16x8*)&As[(wm + i * 16 + fr) * 32 + fk];
#pragma unroll
    for (int j = 0; j < 2; j++)
      bf[j] = *(const bf16x8*)&Bs[(wn + j * 16 + fr) * 32 + fk];
#pragma unroll
    for (int i = 0; i < 4; i++)
#pragma unroll
      for (int j = 0; j < 2; j++)
        acc[i][j] =
            __builtin_amdgcn_mfma_f32_16x16x32_bf16(af[i], bf[j], acc[i][j], 0, 0, 0);
    __syncthreads();
  }

#pragma unroll
  for (int i = 0; i < 4; i++) {
    const int gm = m0 + wm + i * 16 + (lane >> 4) * 4;
#pragma unroll
    for (int j = 0; j < 2; j++) {
      const int gn = n0 + wn + j * 16 + fr;
#pragma unroll
      for (int rix = 0; rix < 4; rix++) {
        float val = acc[i][j][rix];
        if (epi == EPI_TANH) val = tanhf(val);
        else if (epi == EPI_SIGMOID) val = 1.f / (1.f + expf(-val));
        out16[(size_t)(gm + rix) * N + gn] = bf16b(val);
      }
    }
  }
}

// ---------------- merged GEMM kernels ----------------
__global__ __launch_bounds__(256) void big3_k(
    const short* __restrict__ xr, const short* __restrict__ xk,
    const short* __restrict__ xv, const short* __restrict__ wrb,
    const short* __restrict__ wkb, const short* __restrict__ wvb,
    float* __restrict__ r_, float* __restrict__ kbuf,
    float* __restrict__ vbuf, short* __restrict__ vbuf16) {
  __shared__ short smem[2 * 128 * 32];
  const int role = blockIdx.x / 6, bx = blockIdx.x % 6;
  const short* A;
  const short* Bw;
  float* C;
  short* C16 = nullptr;
  if (role == 0) { A = xr; Bw = wrb; C = r_; }
  else if (role == 1) { A = xk; Bw = wkb; C = kbuf; }
  else { A = xv; Bw = wvb; C = vbuf; C16 = vbuf16; }
  gemm128_tile(A, Bw, C, C16, B_ * T_, C_, C_, bx, blockIdx.y, EPI_NONE,
               nullptr, nullptr, nullptr, smem, smem + 128 * 32);
}

__global__ __launch_bounds__(256) void s1x4_k(
    const short* __restrict__ xw, const short* __restrict__ xa,
    const short* __restrict__ xg, const short* __restrict__ vbuf16,
    const short* __restrict__ wAT, const short* __restrict__ aAT,
    const short* __restrict__ gAT, const short* __restrict__ vAT,
    short* __restrict__ h_w, short* __restrict__ h_a,
    short* __restrict__ h_g, short* __restrict__ h_v) {
  __shared__ short smem[128 * 32 + 64 * 32];
  const int bx = blockIdx.x;  // 0..4
  const short* A;
  const short* Bw;
  short* O;
  int N, tb, epi;
  if (bx == 0)      { A = xw;     Bw = wAT; O = h_w; N = 64;  tb = 0; epi = EPI_TANH; }
  else if (bx == 1) { A = xa;     Bw = aAT; O = h_a; N = 64;  tb = 0; epi = EPI_NONE; }
  else if (bx == 2) { A = xg;     Bw = gAT; O = h_g; N = 128; tb = 0; epi = EPI_SIGMOID; }
  else if (bx == 3) { A = xg;     Bw = gAT; O = h_g; N = 128; tb = 1; epi = EPI_SIGMOID; }
  else              { A = vbuf16; Bw = vAT; O = h_v; N = 64;  tb = 0; epi = EPI_NONE; }
  gemm64_tile(A, Bw, O, B_ * T_, N, C_, tb, blockIdx.y, epi, smem,
              smem + 128 * 32);
}

__global__ __launch_bounds__(256) void s2x3_k(
    const short* __restrict__ h_v, const short* __restrict__ h_w,
    const short* __restrict__ h_a, const short* __restrict__ vBT,
    const short* __restrict__ wBT, const short* __restrict__ aBT,
    float* __restrict__ vbuf, float* __restrict__ dec_, float* __restrict__ a_,
    const float* __restrict__ v_miu, const float* __restrict__ w_miu,
    const float* __restrict__ a_miu, const float* __restrict__ v_first) {
  __shared__ short smem[2 * 128 * 32];
  const int role = blockIdx.x / 6, bx = blockIdx.x % 6;
  const short* A;
  const short* Bw;
  float* C;
  const float* bias;
  const float* ex1 = nullptr;
  const float* ex2 = nullptr;
  int epi;
  if (role == 0) { A = h_v; Bw = vBT; C = vbuf; bias = v_miu; ex1 = vbuf; ex2 = v_first; epi = EPI_VMIX; }
  else if (role == 1) { A = h_w; Bw = wBT; C = dec_; bias = w_miu; epi = EPI_WDECAY; }
  else { A = h_a; Bw = aBT; C = a_; bias = a_miu; epi = EPI_SIGBIAS; }
  gemm128_tile(A, Bw, C, nullptr, B_ * T_, C_, 64, bx, blockIdx.y, epi, bias,
               ex1, ex2, smem, smem + 128 * 32);
}

__global__ __launch_bounds__(256) void outp_k(
    const short* __restrict__ ymb, const short* __restrict__ wob,
    float* __restrict__ out) {
  __shared__ short smem[2 * 128 * 32];
  gemm128_tile(ymb, wob, out, nullptr, B_ * T_, C_, C_, blockIdx.x,
               blockIdx.y, EPI_NONE, nullptr, nullptr, nullptr, smem,
               smem + 128 * 32);
}

// ---------------- mix -> bf16 (6 lambdas, one pass) ----------------
__global__ __launch_bounds__(256) void mix6_k(
    const float* __restrict__ x, const float* __restrict__ lr,
    const float* __restrict__ lk, const float* __restrict__ lv,
    const float* __restrict__ lw, const float* __restrict__ la,
    const float* __restrict__ lg, short* __restrict__ xr,
    short* __restrict__ xk, short* __restrict__ xv, short* __restrict__ xw,
    short* __restrict__ xa, short* __restrict__ xg) {
  const int i = blockIdx.x * 256 + threadIdx.x;  // float4 index
  const int c4 = i % (C_ / 4);
  const int gm = i / (C_ / 4);
  const float4 xa4 = ((const float4*)x)[i];
  float4 xp = make_float4(0.f, 0.f, 0.f, 0.f);
  if ((gm % T_) != 0) xp = ((const float4*)x)[i - C_ / 4];
  const float4 dx =
      make_float4(xp.x - xa4.x, xp.y - xa4.y, xp.z - xa4.z, xp.w - xa4.w);

#define MIXOUT(dst, lam)                                                      \
  {                                                                           \
    const float4 l4 = ((const float4*)lam)[c4];                               \
    short4 o = {bf16b(fmaf(dx.x, l4.x, xa4.x)),                               \
                bf16b(fmaf(dx.y, l4.y, xa4.y)),                               \
                bf16b(fmaf(dx.z, l4.z, xa4.z)),                               \
                bf16b(fmaf(dx.w, l4.w, xa4.w))};                              \
    ((short4*)dst)[i] = o;                                                    \
  }
  MIXOUT(xr, lr);
  MIXOUT(xk, lk);
  MIXOUT(xv, lv);
  MIXOUT(xw, lw);
  MIXOUT(xa, la);
  MIXOUT(xg, lg);
#undef MIXOUT
}

// ------------- weights prep: 4 straight converts + 8 transposes ----------
__global__ __launch_bounds__(256) void wprep_k(
    const float* __restrict__ W_r, const float* __restrict__ W_k,
    const float* __restrict__ W_v, const float* __restrict__ W_o,
    const float* __restrict__ w_A, const float* __restrict__ a_A,
    const float* __restrict__ v_A, const float* __restrict__ g_A,
    const float* __restrict__ w_B, const float* __restrict__ a_B,
    const float* __restrict__ v_B, const float* __restrict__ g_B,
    short* __restrict__ wrb, short* __restrict__ wkb,
    short* __restrict__ wvb, short* __restrict__ wob,
    short* __restrict__ wAT, short* __restrict__ aAT,
    short* __restrict__ vAT, short* __restrict__ gAT,
    short* __restrict__ wBT, short* __restrict__ aBT,
    short* __restrict__ vBT, short* __restrict__ gBT) {
  const int job = blockIdx.y;
  const int WN = C_ * C_;
  if (job < 4) {
    const float* src = (job == 0) ? W_r : (job == 1) ? W_k : (job == 2) ? W_v : W_o;
    short* dst = (job == 0) ? wrb : (job == 1) ? wkb : (job == 2) ? wvb : wob;
    const int n4 = WN / 4;
    for (int i = blockIdx.x * 256 + threadIdx.x; i < n4; i += gridDim.x * 256) {
      const float4 v = ((const float4*)src)[i];
      short4 o = {bf16b(v.x), bf16b(v.y), bf16b(v.z), bf16b(v.w)};
      ((short4*)dst)[i] = o;
    }
  } else {
    const float* in;
    short* out;
    int R, Cc;
    switch (job) {
      case 4: in = w_A; out = wAT; R = C_; Cc = 64; break;
      case 5: in = a_A; out = aAT; R = C_; Cc = 64; break;
      case 6: in = v_A; out = vAT; R = C_; Cc = 64; break;
      case 7: in = g_A; out = gAT; R = C_; Cc = 128; break;
      case 8: in = w_B; out = wBT; R = 64; Cc = C_; break;
      case 9: in = a_B; out = aBT; R = 64; Cc = C_; break;
      case 10: in = v_B; out = vBT; R = 64; Cc = C_; break;
      default: in = g_B; out = gBT; R = 128; Cc = C_; break;
    }
    const int n = R * Cc;
    for (int i = blockIdx.x * 256 + threadIdx.x; i < n; i += gridDim.x * 256) {
      const int r = i / Cc, c = i % Cc;
      out[(size_t)c * R + r] = bf16b(in[i]);
    }
  }
}

// ---------------- kk prep: packed bf16 + rk-scalar ----------------
__global__ __launch_bounds__(256) void kkprep_k(
    const float* __restrict__ k0, const float* __restrict__ av_,
    const float* __restrict__ rr, const float* __restrict__ k_k,
    const float* __restrict__ k_a, const float* __restrict__ r_k,
    short* __restrict__ zb16, short* __restrict__ kr16,
    float* __restrict__ s_rk) {
  const int tid = threadIdx.x;
  const int wv = tid >> 6, l = tid & 63;
  const int grp = l >> 4, g16 = l & 15;
  const size_t hid = (size_t)blockIdx.x * 16 + wv * 4 + grp;
  const int h = (int)(hid % H_);
  const size_t base = hid * 64 + g16 * 4;
  const int cc = h * 64 + g16 * 4;

  const float4 kv = *(const float4*)(k0 + base);
  const float4 aa = *(const float4*)(av_ + base);
  const float4 rv = *(const float4*)(rr + base);
  const float4 kkc = *(const float4*)(k_k + cc);
  const float4 kac = *(const float4*)(k_a + cc);
  const float4 rk4 = *(const float4*)(r_k + cc);

  const float kkx = kv.x * kkc.x, kky = kv.y * kkc.y, kkz = kv.z * kkc.z,
              kkw = kv.w * kkc.w;
  const float ssp = kkx * kkx + kky * kky + kkz * kkz + kkw * kkw;
  const float ss = row_sum16(ssp);
  const float denom = fmaxf(sqrtf(ss), 1e-12f);
  const float nx = kkx / denom, ny = kky / denom, nz = kkz / denom,
              nw = kkw / denom;

  bf16x8 zb = {bf16b(-nx), bf16b(-ny), bf16b(-nz), bf16b(-nw),
               bf16b(nx * aa.x), bf16b(ny * aa.y), bf16b(nz * aa.z),
               bf16b(nw * aa.w)};
  *(bf16x8*)(zb16 + hid * 128 + g16 * 8) = zb;

  const float knx = kv.x * (1.f + (aa.x - 1.f) * kac.x);
  const float kny = kv.y * (1.f + (aa.y - 1.f) * kac.y);
  const float knz = kv.z * (1.f + (aa.z - 1.f) * kac.z);
  const float knw = kv.w * (1.f + (aa.w - 1.f) * kac.w);
  bf16x8 kr = {bf16b(knx), bf16b(kny), bf16b(knz), bf16b(knw),
               bf16b(rv.x), bf16b(rv.y), bf16b(rv.z), bf16b(rv.w)};
  *(bf16x8*)(kr16 + hid * 128 + g16 * 8) = kr;

  // rk-scalar for gn: s = sum(r * k_mod * r_k) over the 64 cols
  const float sp = rv.x * knx * rk4.x + rv.y * kny * rk4.y +
                   rv.z * knz * rk4.z + rv.w * knw * rk4.w;
  const float sv = row_sum16(sp);
  if (g16 == 0) s_rk[hid] = sv;
}

// ---------------- phase A: per-chunk summaries (parallel) ----------------
__global__ __launch_bounds__(256) void phaseA_k(
    const float* __restrict__ dd, const short* __restrict__ zb16,
    const short* __restrict__ kr16, short* __restrict__ m16,
    short* __restrict__ Zc16, short* __restrict__ Bc16,
    short* __restrict__ P16, float* __restrict__ Cbuf,
    float* __restrict__ Dbuf) {
  const int tid = threadIdx.x;
  const int wave = tid >> 6, l = tid & 63;
  const int grp = l >> 4, l16 = l & 15;
  const int cid = blockIdx.x * 4 + wave;  // 0..6143
  const int bh = cid >> 7, c = cid & (NCH - 1);
  const int b = bh / H_, h = bh % H_;
  const size_t tok0 = (size_t)b * T_ + (size_t)c * L_;
  const size_t cbase = (size_t)cid * 256;
  const size_t vbase = (size_t)cid * 1024;

#define LD_ZB(s, z4, b4)                                                      \
  {                                                                           \
    const bf16x8 t8 =                                                         \
        *(const bf16x8*)(zb16 + ((tok0 + (s)) * H_ + h) * 128 + l16 * 8);     \
    z4 = make_float4(bf2f(t8[0]), bf2f(t8[1]), bf2f(t8[2]), bf2f(t8[3]));     \
    b4 = make_float4(bf2f(t8[4]), bf2f(t8[5]), bf2f(t8[6]), bf2f(t8[7]));     \
  }
#define LD_KR(s, k4, r4)                                                      \
  {                                                                           \
    const bf16x8 t8 =                                                         \
        *(const bf16x8*)(kr16 + ((tok0 + (s)) * H_ + h) * 128 + l16 * 8);     \
    k4 = make_float4(bf2f(t8[0]), bf2f(t8[1]), bf2f(t8[2]), bf2f(t8[3]));     \
    r4 = make_float4(bf2f(t8[4]), bf2f(t8[5]), bf2f(t8[6]), bf2f(t8[7]));     \
  }
#define LD_D(s, d4)                                                           \
  { d4 = *(const float4*)(dd + (tok0 + (s)) * C_ + h * 64 + l16 * 4); }
#define DOT4(a, b) ((a).x * (b).x + (a).y * (b).y + (a).z * (b).z + (a).w * (b).w)

  for (int tsel = 0; tsel < 4; ++tsel) {
    const int t = tsel * 4 + grp;
    float4 k4, x;
    LD_KR(t, k4, x);  // x = r_t
    {
      const float cs = row_sum16(DOT4(k4, x));
      if (l16 == 0) Cbuf[cbase + t * 16 + t] = cs;
    }
    for (int s = t; s >= 1; --s) {
      float4 z4, b4, d4, ki, ri;
      LD_ZB(s, z4, b4);
      LD_D(s, d4);
      const float bd = row_sum16(DOT4(b4, x));
      x.x = fmaf(d4.x, x.x, z4.x * bd);
      x.y = fmaf(d4.y, x.y, z4.y * bd);
      x.z = fmaf(d4.z, x.z, z4.z * bd);
      x.w = fmaf(d4.w, x.w, z4.w * bd);
      LD_KR(s - 1, ki, ri);
      const float cv = row_sum16(DOT4(ki, x));
      if (l16 == 0) Cbuf[cbase + t * 16 + (s - 1)] = cv;
    }
    {  // m_t = A_0 x
      float4 z4, b4, d4;
      LD_ZB(0, z4, b4);
      LD_D(0, d4);
      const float bd = row_sum16(DOT4(b4, x));
      x.x = fmaf(d4.x, x.x, z4.x * bd);
      x.y = fmaf(d4.y, x.y, z4.y * bd);
      x.z = fmaf(d4.z, x.z, z4.z * bd);
      x.w = fmaf(d4.w, x.w, z4.w * bd);
      short4 o = {bf16b(x.x), bf16b(x.y), bf16b(x.z), bf16b(x.w)};
      *(short4*)(m16 + vbase + t * 64 + l16 * 4) = o;
    }
  }

  for (int isel = 0; isel < 4; ++isel) {
    const int i = isel * 4 + grp;
    float4 xp, xb;
    {
      float4 k4, r4;
      LD_KR(i, k4, r4);
      xp = k4;
    }
    {
      float4 z4, b4;
      LD_ZB(i, z4, b4);
      xb = b4;
    }
    for (int s = i + 1; s < L_; ++s) {
      float4 z4, b4, d4;
      LD_ZB(s, z4, b4);
      LD_D(s, d4);
      const float sp = row_sum16(DOT4(z4, xp));
      const float sb = row_sum16(DOT4(z4, xb));
      xp.x = fmaf(d4.x, xp.x, b4.x * sp);
      xp.y = fmaf(d4.y, xp.y, b4.y * sp);
      xp.z = fmaf(d4.z, xp.z, b4.z * sp);
      xp.w = fmaf(d4.w, xp.w, b4.w * sp);
      xb.x = fmaf(d4.x, xb.x, b4.x * sb);
      xb.y = fmaf(d4.y, xb.y, b4.y * sb);
      xb.z = fmaf(d4.z, xb.z, b4.z * sb);
      xb.w = fmaf(d4.w, xb.w, b4.w * sb);
    }
    {
      short4 op = {bf16b(xp.x), bf16b(xp.y), bf16b(xp.z), bf16b(xp.w)};
      short4 ob = {bf16b(xb.x), bf16b(xb.y), bf16b(xb.z), bf16b(xb.w)};
      *(short4*)(P16 + vbase + i * 64 + l16 * 4) = op;
      *(short4*)(Bc16 + vbase + i * 64 + l16 * 4) = ob;
    }
  }

  {
    float4 prod = make_float4(1.f, 1.f, 1.f, 1.f);
    for (int s = 0; s < L_; ++s) {
      if ((s & 3) == grp) {
        float4 z4, b4;
        LD_ZB(s, z4, b4);
        short4 o = {bf16b(prod.x * z4.x), bf16b(prod.y * z4.y),
                    bf16b(prod.z * z4.z), bf16b(prod.w * z4.w)};
        *(short4*)(Zc16 + vbase + s * 64 + l16 * 4) = o;
      }
      float4 d4;
      LD_D(s, d4);
      prod.x *= d4.x;
      prod.y *= d4.y;
      prod.z *= d4.z;
      prod.w *= d4.w;
    }
    if (grp == 0)
      *(float4*)(Dbuf + (size_t)cid * 64 + l16 * 4) = prod;
  }
#undef LD_ZB
#undef LD_KR
#undef LD_D
#undef DOT4
}

// ---------------- phase B: 48 chain blocks x 4 column-quarter waves ------
// Blocks 0..47: chain (wave = state column quarter nt; all shuffle gathers
// intra-wave; summaries staged to LDS cooperatively). Blocks 48..95: s2-g
// GEMM. Blocks 96..111: v_first copy.
#define MFMA32(a, b, c) __builtin_amdgcn_mfma_f32_16x16x32_bf16(a, b, c, 0, 0, 0)
__global__ __launch_bounds__(256) void phaseB_k(
    const short* __restrict__ m16, const short* __restrict__ Zc16,
    const short* __restrict__ Bc16, const short* __restrict__ P16,
    const float* __restrict__ Cbuf, const float* __restrict__ Dbuf,
    const float* __restrict__ vbuf, float* __restrict__ yy,
    const short* __restrict__ h_g, const short* __restrict__ gBT,
    float* __restrict__ g_, const float4* __restrict__ cpsrc,
    float4* __restrict__ cpdst, int n4) {
  __shared__ __align__(16) char smem[16384];
  const int blk = blockIdx.x;

  if (blk >= 96) {  // ---- copy role ----
    const int rb = blk - 96;
    for (int i = rb * 256 + threadIdx.x; i < n4; i += 16 * 256)
      cpdst[i] = cpsrc[i];
    return;
  }
  if (blk >= 48) {  // ---- stage2-g GEMM role ----
    short* As = (short*)smem;
    short* Bs = As + 128 * 32;
    const int rb = blk - 48;
    for (int it = 0; it < 8; ++it) {
      const int tile = rb + it * 48;
      gemm128_tile(h_g, gBT, g_, nullptr, B_ * T_, C_, 128, tile % 6,
                   tile / 6, EPI_NONE, nullptr, nullptr, nullptr, As, Bs);
    }
    return;
  }

  // ---- chain role ----
  const int bh = blk;  // 0..47
  const int b = bh / H_, h = bh % H_;
  const int tid = threadIdx.x;
  const int wave = tid >> 6, l = tid & 63;
  const int nt = wave;  // column quarter
  const int q = l >> 4, n16 = l & 15;

  short* Lm = (short*)smem;
  short* LZc = (short*)(smem + 2048);
  short* LBc = (short*)(smem + 4096);
  short* LP = (short*)(smem + 6144);
  float* Lv = (float*)(smem + 8192);
  float* LC = (float*)(smem + 12288);
  float* LD = (float*)(smem + 13312);

  f32x4 acc[4];
#pragma unroll
  for (int i = 0; i < 4; i++) acc[i] = (f32x4){0.f, 0.f, 0.f, 0.f};

  for (int c = 0; c < NCH; ++c) {
    const size_t cid = (size_t)bh * NCH + c;
    const size_t t0g = (size_t)b * T_ + (size_t)c * L_;
    const size_t vb = cid * 1024;

    // ---- cooperative staging (per-lane coalesced) ----
    if (wave == 0) {
      GLD16(m16 + vb + l * 8, Lm);
      GLD16(m16 + vb + 512 + l * 8, (char*)Lm + 1024);
      GLD16(Cbuf + cid * 256 + l * 4, LC);
      if (l < 16) GLD16(Dbuf + cid * 64 + (size_t)l * 4, LD);
    } else if (wave == 1) {
      GLD16(Zc16 + vb + l * 8, LZc);
      GLD16(Zc16 + vb + 512 + l * 8, (char*)LZc + 1024);
      GLD16(vbuf + (t0g + (l >> 4)) * C_ + h * 64 + (l & 15) * 4, Lv);
      GLD16(vbuf + (t0g + 12 + (l >> 4)) * C_ + h * 64 + (l & 15) * 4,
            (char*)Lv + 3072);
    } else if (wave == 2) {
      GLD16(Bc16 + vb + l * 8, LBc);
      GLD16(Bc16 + vb + 512 + l * 8, (char*)LBc + 1024);
      GLD16(vbuf + (t0g + 4 + (l >> 4)) * C_ + h * 64 + (l & 15) * 4,
            (char*)Lv + 1024);
    } else {
      GLD16(P16 + vb + l * 8, LP);
      GLD16(P16 + vb + 512 + l * 8, (char*)LP + 1024);
      GLD16(vbuf + (t0g + 8 + (l >> 4)) * C_ + h * 64 + (l & 15) * 4,
            (char*)Lv + 2048);
    }
    __syncthreads();

    // 1) St0 -> B-operand frags (verbatim R15, nt fixed)
    bf16x8 sf[2];
#pragma unroll
    for (int kt2 = 0; kt2 < 2; ++kt2) {
      bf16x8 f;
#pragma unroll
      for (int e = 0; e < 8; ++e) {
        const int src = n16 + ((e >> 2) + ((q & 1) << 1)) * 16;
        const float v0 = __shfl(acc[2 * kt2 + 0][e & 3], src);
        const float v1 = __shfl(acc[2 * kt2 + 1][e & 3], src);
        f[e] = bf16b((q < 2) ? v0 : v1);
      }
      sf[kt2] = f;
    }

    // 2) V^T B-frag for own nt
    bf16x8 bv;
    {
      bf16x8 f;
#pragma unroll
      for (int e = 0; e < 8; ++e) {
        const int k = q * 8 + e;
        float v = 0.f;
        if (k < L_) v = Lv[k * 64 + nt * 16 + n16];
        f[e] = bf16b(v);
      }
      bv = f;
    }

    // 3) Y^T = Mm^T St0 + C^T V^T
    {
      f32x4 yac = (f32x4){0.f, 0.f, 0.f, 0.f};
      bf16x8 am0 = *(const bf16x8*)(Lm + n16 * 64 + 0 * 32 + q * 8);
      bf16x8 am1 = *(const bf16x8*)(Lm + n16 * 64 + 1 * 32 + q * 8);
      bf16x8 ac;
      {
        float4 c0 = make_float4(0.f, 0.f, 0.f, 0.f), c1 = c0;
        if (q < 2) {
          const float* cp = LC + n16 * 16 + q * 8;
          c0 = *(const float4*)cp;
          c1 = *(const float4*)(cp + 4);
        }
        const float cf[8] = {c0.x, c0.y, c0.z, c0.w, c1.x, c1.y, c1.z, c1.w};
#pragma unroll
        for (int e = 0; e < 8; ++e) {
          const int i = q * 8 + e;
          ac[e] = (q < 2 && i <= n16) ? bf16b(cf[e]) : (short)0;
        }
      }
      yac = MFMA32(am0, sf[0], yac);
      yac = MFMA32(am1, sf[1], yac);
      yac = MFMA32(ac, bv, yac);
#pragma unroll
      for (int rix = 0; rix < 4; ++rix)
        yy[(t0g + q * 4 + rix) * C_ + h * 64 + nt * 16 + n16] = yac[rix];
    }

    // 4) W = Zc^T St0
    f32x4 wac = (f32x4){0.f, 0.f, 0.f, 0.f};
    {
      bf16x8 az0 = *(const bf16x8*)(LZc + n16 * 64 + 0 * 32 + q * 8);
      bf16x8 az1 = *(const bf16x8*)(LZc + n16 * 64 + 1 * 32 + q * 8);
      wac = MFMA32(az0, sf[0], wac);
      wac = MFMA32(az1, sf[1], wac);
    }

    // 5) St' = diag(D) St0 + Bc W + P V^T
#pragma unroll
    for (int mt = 0; mt < 4; ++mt) {
      const float4 dv = *(const float4*)(LD + mt * 16 + q * 4);
      acc[mt][0] *= dv.x;
      acc[mt][1] *= dv.y;
      acc[mt][2] *= dv.z;
      acc[mt][3] *= dv.w;
    }
    bf16x8 wf;
    {
      bf16x8 f;
#pragma unroll
      for (int e = 0; e < 8; ++e) {
        const int src = n16 + (((q & 1) << 1) + (e >> 2)) * 16;
        const float v = __shfl(wac[e & 3], src);
        f[e] = (q < 2) ? bf16b(v) : (short)0;
      }
      wf = f;
    }
#pragma unroll
    for (int mt = 0; mt < 4; ++mt) {
      bf16x8 fb, fp;
#pragma unroll
      for (int e = 0; e < 8; ++e) {
        const int k = q * 8 + e;
        short vbv = 0, vpv = 0;
        if (k < L_) {
          vbv = LBc[k * 64 + mt * 16 + n16];
          vpv = LP[k * 64 + mt * 16 + n16];
        }
        fb[e] = vbv;
        fp[e] = vpv;
      }
      acc[mt] = MFMA32(fb, wf, acc[mt]);
      acc[mt] = MFMA32(fp, bv, acc[mt]);
    }
    __syncthreads();
  }
}

// ---------- GroupNorm + rk-scalar + gate -> bf16 ----------
__global__ __launch_bounds__(256) void gn_k(
    const float* __restrict__ y, const float* __restrict__ v,
    const float* __restrict__ g, const float* __restrict__ s_rk,
    const float* __restrict__ ln_w, const float* __restrict__ ln_b,
    short* __restrict__ ymb) {
  const int tid = threadIdx.x;
  const int wv = tid >> 6, l = tid & 63;
  const int grp = l >> 4, g16 = l & 15;
  const size_t hid = (size_t)blockIdx.x * 16 + wv * 4 + grp;
  const int h = (int)(hid % H_);
  const size_t base = hid * 64 + g16 * 4;
  const int cc = h * 64 + g16 * 4;

  const float4 y4 = *(const float4*)(y + base);
  const float4 v4 = *(const float4*)(v + base);
  const float4 g4 = *(const float4*)(g + base);
  const float4 lw4 = *(const float4*)(ln_w + cc);
  const float4 lb4 = *(const float4*)(ln_b + cc);
  const float s = s_rk[hid];

  const float mu = row_sum16(y4.x + y4.y + y4.z + y4.w) * (1.f / 64.f);
  const float sq =
      row_sum16(y4.x * y4.x + y4.y * y4.y + y4.z * y4.z + y4.w * y4.w) *
      (1.f / 64.f);
  const float inv = rsqrtf(sq - mu * mu + 0.00064f);

  short4 o;
  o.x = bf16b((fmaf((y4.x - mu) * inv, lw4.x, fmaf(s, v4.x, lb4.x))) * g4.x);
  o.y = bf16b((fmaf((y4.y - mu) * inv, lw4.y, fmaf(s, v4.y, lb4.y))) * g4.y);
  o.z = bf16b((fmaf((y4.z - mu) * inv, lw4.z, fmaf(s, v4.z, lb4.z))) * g4.z);
  o.w = bf16b((fmaf((y4.w - mu) * inv, lw4.w, fmaf(s, v4.w, lb4.w))) * g4.w);
  *(short4*)(ymb + base) = o;
}

// ---------------- host launcher ----------------
extern "C" void kernel_launch(void* const* d_in, const int* in_sizes, int n_in,
                              void* d_out, int out_size, void* d_ws,
                              size_t ws_size, hipStream_t stream) {
  const float* x       = (const float*)d_in[0];
  const float* v_first = (const float*)d_in[1];
  const float* lam_r   = (const float*)d_in[2];
  const float* lam_w   = (const float*)d_in[3];
  const float* lam_k   = (const float*)d_in[4];
  const float* lam_v   = (const float*)d_in[5];
  const float* lam_a   = (const float*)d_in[6];
  const float* lam_g   = (const float*)d_in[7];
  const float* w_miu   = (const float*)d_in[8];
  const float* w_A     = (const float*)d_in[9];
  const float* w_B     = (const float*)d_in[10];
  const float* a_miu   = (const float*)d_in[11];
  const float* a_A     = (const float*)d_in[12];
  const float* a_B     = (const float*)d_in[13];
  const float* v_miu   = (const float*)d_in[14];
  const float* v_A     = (const float*)d_in[15];
  const float* v_B     = (const float*)d_in[16];
  const float* g_A     = (const float*)d_in[17];
  const float* g_B     = (const float*)d_in[18];
  const float* k_k     = (const float*)d_in[19];
  const float* k_a     = (const float*)d_in[20];
  const float* r_k     = (const float*)d_in[21];
  const float* W_r     = (const float*)d_in[22];
  const float* W_k     = (const float*)d_in[23];
  const float* W_v     = (const float*)d_in[24];
  const float* W_o     = (const float*)d_in[25];
  const float* ln_w    = (const float*)d_in[26];
  const float* ln_b    = (const float*)d_in[27];

  const int M = B_ * T_;            // 8192
  const size_t S = (size_t)M * C_;  // 6291456

  float* ws   = (float*)d_ws;
  float* r_   = ws + 0 * S;
  float* kbuf = ws + 1 * S;
  float* vbuf = ws + 2 * S;
  float* dec_ = ws + 3 * S;
  float* a_   = ws + 4 * S;
  float* g_   = ws + 5 * S;
  float* z_   = ws + 6 * S;
  float* bb_  = ws + 7 * S;
  float* h_   = ws + 8 * S;                       // M*128 floats
  short* wb   = (short*)(h_ + (size_t)M * 128);   // bf16 weight copies
  float* out  = (float*)d_out;

  const int WN = C_ * C_;  // 589824
  short* wrb = wb + 0 * (size_t)WN;
  short* wkb = wb + 1 * (size_t)WN;
  short* wvb = wb + 2 * (size_t)WN;
  short* wob = wb + 3 * (size_t)WN;
  short* wAT = wb + 4 * (size_t)WN;
  short* aAT = wAT + (size_t)C_ * 64;
  short* vAT = aAT + (size_t)C_ * 64;
  short* gAT = vAT + (size_t)C_ * 64;
  short* wBT = gAT + (size_t)C_ * 128;
  short* aBT = wBT + (size_t)C_ * 64;
  short* vBT = aBT + (size_t)C_ * 64;
  short* gBT = vBT + (size_t)C_ * 64;

  // bf16 aliases in dead fp32 slots
  short* xr  = (short*)dec_;
  short* xk  = (short*)a_;
  short* xv  = (short*)g_;
  short* xw  = (short*)z_;
  short* xa  = (short*)z_ + S;
  short* xg  = (short*)bb_;
  short* vbuf16 = (short*)bb_ + S;
  short* h_w = (short*)h_;
  short* h_a = h_w + (size_t)M * 64;
  short* h_g = h_a + (size_t)M * 64;
  short* h_v = (short*)g_;
  short* zb16 = (short*)z_;
  short* kr16 = (short*)bb_;
  short* ymb = (short*)z_;

  // chunk summaries in slots dead after kkprep
  short* m16  = (short*)kbuf;
  short* Zc16 = m16 + S;
  short* Bc16 = (short*)r_;
  short* P16  = Bc16 + S;
  float* Cbuf = out;
  float* Dbuf = Cbuf + (size_t)NCID * 256;
  float* s_rk = Dbuf + (size_t)NCID * 64;

  // 1) weights prep
  {
    dim3 blk(256), grid(576, 12);
    hipLaunchKernelGGL(wprep_k, grid, blk, 0, stream, W_r, W_k, W_v, W_o,
                       w_A, a_A, v_A, g_A, w_B, a_B, v_B, g_B, wrb, wkb, wvb,
                       wob, wAT, aAT, vAT, gAT, wBT, aBT, vBT, gBT);
  }
  // 2) mix
  {
    dim3 blk(256), grid((int)(S / 4 / 256));
    hipLaunchKernelGGL(mix6_k, grid, blk, 0, stream, x, lam_r, lam_k, lam_v,
                       lam_w, lam_a, lam_g, xr, xk, xv, xw, xa, xg);
  }
  // 3) big projections
  {
    dim3 blk(256), grid(18, M / 128);
    hipLaunchKernelGGL(big3_k, grid, blk, 0, stream, xr, xk, xv, wrb, wkb,
                       wvb, r_, kbuf, vbuf, vbuf16);
  }
  // 4) stage-1 low-rank
  {
    dim3 blk(256), grid(5, M / 128);
    hipLaunchKernelGGL(s1x4_k, grid, blk, 0, stream, xw, xa, xg, vbuf16, wAT,
                       aAT, gAT, vAT, h_w, h_a, h_g, h_v);
  }
  // 5) stage-2 VMIX/WDECAY/SIGBIAS
  {
    dim3 blk(256), grid(18, M / 128);
    hipLaunchKernelGGL(s2x3_k, grid, blk, 0, stream, h_v, h_w, h_a, vBT, wBT,
                       aBT, vbuf, dec_, a_, v_miu, w_miu, a_miu, v_first);
  }
  // 6) kk prep -> zb16/kr16 + s_rk
  {
    dim3 grid((B_ * T_ * H_) / 16), blk(256);
    hipLaunchKernelGGL(kkprep_k, grid, blk, 0, stream, kbuf, a_, r_, k_k,
                       k_a, r_k, zb16, kr16, s_rk);
  }
  // 7) phase A: per-chunk summaries (parallel)
  {
    dim3 grid(NCID / 4), blk(256);
    hipLaunchKernelGGL(phaseA_k, grid, blk, 0, stream, dec_, zb16, kr16,
                       m16, Zc16, Bc16, P16, Cbuf, Dbuf);
  }
  // 8) phase B: chain blocks (col-split waves, LDS-staged) + s2g + copy
  {
    dim3 grid(112), blk(256);
    hipLaunchKernelGGL(phaseB_k, grid, blk, 0, stream, m16, Zc16, Bc16, P16,
                       Cbuf, Dbuf, vbuf, a_, h_g, gBT, g_,
                       (const float4*)v_first, (float4*)(out + S),
                       (int)(S / 4));
  }
  // 9) groupnorm + rk-scalar + gate
  {
    dim3 grid((B_ * T_ * H_) / 16), blk(256);
    hipLaunchKernelGGL(gn_k, grid, blk, 0, stream, a_, vbuf, g_, s_rk,
                       ln_w, ln_b, ymb);
  }
  // 10) output projection
  {
    dim3 blk(256), grid(C_ / 128, M / 128);
    hipLaunchKernelGGL(outp_k, grid, blk, 0, stream, ymb, wob, out);
  }
}